// Round 6
// baseline (347.815 us; speedup 1.0000x reference)
//
#include <hip/hip_runtime.h>
#include <hip/hip_fp16.h>

#define HD 128
#define BSH 9              // 512 dst-nodes per bucket
#define NBLKA 128          // phase-A persistent blocks
#define CAP 160            // per (block,bucket) cell capacity (mean ~64)

typedef _Float16 half8_t __attribute__((ext_vector_type(8)));
typedef float floatx4 __attribute__((ext_vector_type(4)));

__device__ inline unsigned pack_h2(float x, float y) {
  __half2 h = __floats2half2_rn(x, y);
  return __builtin_bit_cast(unsigned, h);
}
__device__ inline float2 up_h2(unsigned u) {
  __half2 h = __builtin_bit_cast(__half2, u);
  return __half22float2(h);
}

__device__ inline void fma8(float* acc, uint4 r, float w) {
  float2 f;
  f = up_h2(r.x); acc[0] = fmaf(w, f.x, acc[0]); acc[1] = fmaf(w, f.y, acc[1]);
  f = up_h2(r.y); acc[2] = fmaf(w, f.x, acc[2]); acc[3] = fmaf(w, f.y, acc[3]);
  f = up_h2(r.z); acc[4] = fmaf(w, f.x, acc[4]); acc[5] = fmaf(w, f.y, acc[5]);
  f = up_h2(r.w); acc[6] = fmaf(w, f.x, acc[6]); acc[7] = fmaf(w, f.y, acc[7]);
}

// ---------- phase A: block-private bucket append (no global atomics) ----------
__global__ __launch_bounds__(256) void k_bucketA(const int* __restrict__ src,
                                                 const int* __restrict__ dst, int E, int nbuck,
                                                 unsigned* __restrict__ bpool,
                                                 int* __restrict__ counts) {
  __shared__ int cnt[512];
  for (int i = threadIdx.x; i < nbuck; i += 256) cnt[i] = 0;
  __syncthreads();
  int blk = blockIdx.x;
  int chunk = (E + NBLKA - 1) / NBLKA;
  int lo = blk * chunk, hi = min(E, lo + chunk);
  for (int i = lo + threadIdx.x; i < hi; i += 256) {
    int s = src[i], d = dst[i];
    int b = d >> BSH;
    int c = atomicAdd(&cnt[b], 1);
    if (c < CAP)
      bpool[((size_t)b * NBLKA + blk) * CAP + c] =
          ((unsigned)(d & ((1 << BSH) - 1)) << 23) | (unsigned)s;
  }
  __syncthreads();
  for (int b = threadIdx.x; b < nbuck; b += 256) counts[(size_t)b * NBLKA + blk] = cnt[b];
}

// ---- phase B1: per-bucket histogram -> dinv, bucket-local exclusive rowptr, bucket total ----
__global__ __launch_bounds__(256) void k_bhist(const unsigned* __restrict__ bpool,
                                               const int* __restrict__ counts,
                                               int n, float* __restrict__ dinv,
                                               int* __restrict__ rowptrL,
                                               int* __restrict__ btot) {
  __shared__ int hist[1 << BSH];
  __shared__ int wsum[256];
  __shared__ int ccache[NBLKA];
  int b = blockIdx.x;
  int base = b << BSH;
  int nn = min(1 << BSH, n - base);
  for (int i = threadIdx.x; i < (1 << BSH); i += 256) hist[i] = 0;
  for (int i = threadIdx.x; i < NBLKA; i += 256)
    ccache[i] = min(counts[(size_t)b * NBLKA + i], CAP);
  __syncthreads();
  int w = threadIdx.x >> 6, lane = threadIdx.x & 63;
  for (int blk = w; blk < NBLKA; blk += 4) {
    int c = ccache[blk];
    const unsigned* seg = bpool + ((size_t)b * NBLKA + blk) * CAP;
    for (int i = lane; i < c; i += 64) atomicAdd(&hist[seg[i] >> 23], 1);
  }
  __syncthreads();
  int t = threadIdx.x;
  int a0 = hist[2 * t], a1 = hist[2 * t + 1];
  int s = a0 + a1;
  wsum[t] = s;
  __syncthreads();
  for (int off = 1; off < 256; off <<= 1) {
    int v = (t >= off) ? wsum[t - off] : 0;
    __syncthreads();
    wsum[t] += v;
    __syncthreads();
  }
  int excl = wsum[t] - s;
  if (2 * t < nn) {
    rowptrL[base + 2 * t] = excl;
    dinv[base + 2 * t] = 1.0f / sqrtf((float)(a0 + 1));
  }
  if (2 * t + 1 < nn) {
    rowptrL[base + 2 * t + 1] = excl + a0;
    dinv[base + 2 * t + 1] = 1.0f / sqrtf((float)(a1 + 1));
  }
  if (t == 255) btot[b] = wsum[255];
}

// ---------- tiny scan of bucket totals (nbuck <= 256) ----------
__global__ __launch_bounds__(256) void k_scanB(int* btot, int nbuck, int* rowptr, int n, int E) {
  __shared__ int tmp[256];
  int t = threadIdx.x;
  int v = (t < nbuck) ? btot[t] : 0;
  tmp[t] = v;
  __syncthreads();
  for (int off = 1; off < 256; off <<= 1) {
    int x = (t >= off) ? tmp[t - off] : 0;
    __syncthreads();
    tmp[t] += x;
    __syncthreads();
  }
  if (t < nbuck) btot[t] = tmp[t] - v;  // exclusive bucket base
  if (t == 0) rowptr[n] = E;
}

// ---- phase B2: per-bucket CSR fill; finalizes rowptr = rowptrL + bucket base (in place) ----
__global__ __launch_bounds__(256) void k_bfill(const unsigned* __restrict__ bpool,
                                               const int* __restrict__ counts,
                                               int* __restrict__ rowptr,  // in: local, out: final
                                               const int* __restrict__ btot,
                                               const float* __restrict__ dinv,
                                               int n, uint2* __restrict__ pair) {
  __shared__ int cur[1 << BSH];
  __shared__ float dloc[1 << BSH];
  __shared__ int ccache[NBLKA];
  int b = blockIdx.x;
  int base = b << BSH;
  int nn = min(1 << BSH, n - base);
  int bb = btot[b];
  for (int i = threadIdx.x; i < nn; i += 256) {
    int c = rowptr[base + i] + bb;
    cur[i] = c;
    rowptr[base + i] = c;  // finalize global rowptr
    dloc[i] = dinv[base + i];
  }
  for (int i = threadIdx.x; i < NBLKA; i += 256)
    ccache[i] = min(counts[(size_t)b * NBLKA + i], CAP);
  __syncthreads();
  int w = threadIdx.x >> 6, lane = threadIdx.x & 63;
  for (int blk = w; blk < NBLKA; blk += 4) {
    int c = ccache[blk];
    const unsigned* seg = bpool + ((size_t)b * NBLKA + blk) * CAP;
    for (int i = lane; i < c; i += 64) {
      unsigned pk = seg[i];
      int dl = pk >> 23;
      int s = pk & 0x7FFFFF;
      int pos = atomicAdd(&cur[dl], 1);
      uint2 pr;
      pr.x = (unsigned)s;
      pr.y = __float_as_uint(dinv[s] * dloc[dl]);
      pair[pos] = pr;
    }
  }
}

// ---------- fused prep: W frag pre-pack | embedding gather | center indices ----------
__global__ __launch_bounds__(256) void k_prep(const float* __restrict__ conv_w,
                                              uint4* __restrict__ wfrag,
                                              const int* __restrict__ z,
                                              const float4* __restrict__ emb,
                                              uint2* __restrict__ xh,
                                              const int* __restrict__ batch,
                                              int* __restrict__ ci,
                                              int n, int embBlocks) {
  int b = blockIdx.x;
  if (b < 24) {  // ---- wprep: 24*256 = 6144 = 3*2*4*4*64 ----
    int t = b * 256 + threadIdx.x;
    int lane = t & 63;
    int s = (t >> 6) & 3;
    int c4 = (t >> 8) & 3;
    int chalf = (t >> 10) & 1;
    int layer = t >> 11;
    int col = chalf * 64 + c4 * 16 + (lane & 15);
    int k0 = s * 32 + (lane >> 4) * 8;
    const float* W = conv_w + (size_t)layer * HD * HD;
    unsigned u[4];
#pragma unroll
    for (int j = 0; j < 4; ++j)
      u[j] = pack_h2(W[(size_t)(k0 + 2 * j) * HD + col], W[(size_t)(k0 + 2 * j + 1) * HD + col]);
    uint4 o; o.x = u[0]; o.y = u[1]; o.z = u[2]; o.w = u[3];
    wfrag[t] = o;
  } else if (b < 24 + embBlocks) {  // ---- embed ----
    int idx = (b - 24) * 256 + threadIdx.x;
    if (idx >= n * 32) return;
    int node = idx >> 5, q = idx & 31;
    float4 v = emb[(size_t)z[node] * 32 + q];
    uint2 o;
    o.x = pack_h2(v.x, v.y);
    o.y = pack_h2(v.z, v.w);
    xh[idx] = o;
  } else {  // ---- ci ----
    int i = (b - 24 - embBlocks) * 256 + threadIdx.x;
    if (i >= n) return;
    if (i == 0 || batch[i] != batch[i - 1]) ci[batch[i]] = i;
  }
}

// ---------- MFMA GEMM ----------
__global__ __launch_bounds__(256) void k_gemm_mfma(const uint4* __restrict__ Xh,
                                                   const uint4* __restrict__ wfrag,
                                                   uint2* __restrict__ Yh,
                                                   int n, int nwaves) {
  int lane = threadIdx.x & 63;
  int gw = blockIdx.x * 4 + (threadIdx.x >> 6);
  int chalf = gw & 1;
  int nrb = (n + 15) >> 4;

  half8_t wf[16];
#pragma unroll
  for (int i = 0; i < 16; ++i) {
    uint4 t = wfrag[((chalf * 4 + (i >> 2)) * 4 + (i & 3)) * 64 + lane];
    wf[i] = __builtin_bit_cast(half8_t, t);
  }

  for (int rb = gw >> 1; rb < nrb; rb += (nwaves >> 1)) {
    int row0 = rb * 16;
    int xr = row0 + (lane & 15);
    if (xr > n - 1) xr = n - 1;
    const uint4* xrow = Xh + (size_t)xr * 16;
    half8_t bf[4];
#pragma unroll
    for (int s = 0; s < 4; ++s)
      bf[s] = __builtin_bit_cast(half8_t, xrow[s * 4 + (lane >> 4)]);
    floatx4 acc[4];
#pragma unroll
    for (int c4 = 0; c4 < 4; ++c4) acc[c4] = (floatx4){0.f, 0.f, 0.f, 0.f};
#pragma unroll
    for (int s = 0; s < 4; ++s) {
#pragma unroll
      for (int c4 = 0; c4 < 4; ++c4)
        acc[c4] = __builtin_amdgcn_mfma_f32_16x16x32_f16(wf[c4 * 4 + s], bf[s], acc[c4], 0, 0, 0);
    }
    int orow = row0 + (lane & 15);
    if (orow < n) {
#pragma unroll
      for (int c4 = 0; c4 < 4; ++c4) {
        int colbase = chalf * 64 + c4 * 16 + (lane >> 4) * 4;
        uint2 o;
        o.x = pack_h2(acc[c4][0], acc[c4][1]);
        o.y = pack_h2(acc[c4][2], acc[c4][3]);
        Yh[(size_t)orow * 32 + (colbase >> 2)] = o;
      }
    }
  }
}

// ---------- aggregate: 16 lanes/row, 8-deep gather pipeline ----------
__global__ __launch_bounds__(256) void k_agg(const uint4* __restrict__ H,
                                             const int* __restrict__ rowptr,
                                             const uint2* __restrict__ pair,
                                             const float* __restrict__ dinv,
                                             const float* __restrict__ bias,
                                             uint4* __restrict__ Out, int n, int relu) {
  int li = threadIdx.x & 15;
  int node = blockIdx.x * 16 + (threadIdx.x >> 4);
  if (node >= n) return;
  float di = dinv[node];
  uint4 srow = H[(size_t)node * 16 + li];
  float acc[8] = {0.f, 0.f, 0.f, 0.f, 0.f, 0.f, 0.f, 0.f};
  fma8(acc, srow, di * di);
  int e = rowptr[node], end = rowptr[node + 1];
  const unsigned long long* pr64 = (const unsigned long long*)pair;
  for (; e + 7 < end; e += 8) {
    unsigned long long p[8];
#pragma unroll
    for (int j = 0; j < 8; ++j) p[j] = __builtin_nontemporal_load(&pr64[e + j]);
    uint4 r[8];
#pragma unroll
    for (int j = 0; j < 8; ++j) r[j] = H[(size_t)(unsigned)(p[j] & 0xFFFFFFFFu) * 16 + li];
#pragma unroll
    for (int j = 0; j < 8; ++j) fma8(acc, r[j], __uint_as_float((unsigned)(p[j] >> 32)));
  }
  for (; e + 1 < end; e += 2) {
    unsigned long long p0 = pr64[e], p1 = pr64[e + 1];
    uint4 r0 = H[(size_t)(unsigned)(p0 & 0xFFFFFFFFu) * 16 + li];
    uint4 r1 = H[(size_t)(unsigned)(p1 & 0xFFFFFFFFu) * 16 + li];
    fma8(acc, r0, __uint_as_float((unsigned)(p0 >> 32)));
    fma8(acc, r1, __uint_as_float((unsigned)(p1 >> 32)));
  }
  if (e < end) {
    unsigned long long p0 = pr64[e];
    uint4 r0 = H[(size_t)(unsigned)(p0 & 0xFFFFFFFFu) * 16 + li];
    fma8(acc, r0, __uint_as_float((unsigned)(p0 >> 32)));
  }
  float4 b0 = ((const float4*)bias)[2 * li];
  float4 b1 = ((const float4*)bias)[2 * li + 1];
  acc[0] += b0.x; acc[1] += b0.y; acc[2] += b0.z; acc[3] += b0.w;
  acc[4] += b1.x; acc[5] += b1.y; acc[6] += b1.z; acc[7] += b1.w;
  if (relu) {
#pragma unroll
    for (int q = 0; q < 8; ++q) acc[q] = fmaxf(acc[q], 0.f);
  }
  uint4 o;
  o.x = pack_h2(acc[0], acc[1]);
  o.y = pack_h2(acc[2], acc[3]);
  o.z = pack_h2(acc[4], acc[5]);
  o.w = pack_h2(acc[6], acc[7]);
  Out[(size_t)node * 16 + li] = o;
}

// ---------- head ----------
__global__ __launch_bounds__(128) void k_head(const __half* __restrict__ X,
                                              const int* __restrict__ ci,
                                              const float* __restrict__ W1,
                                              const float* __restrict__ b1,
                                              const float* __restrict__ w2,
                                              const float* __restrict__ b2,
                                              float* __restrict__ out, int G) {
  __shared__ float xs[HD];
  __shared__ float red[HD];
  int g = blockIdx.x;
  int t = threadIdx.x;
  int c = ci[g];
  xs[t] = __half2float(X[(size_t)c * HD + t]) * __half2float(X[(size_t)(c + 1) * HD + t]);
  __syncthreads();
  float acc = b1[t];
#pragma unroll 8
  for (int k = 0; k < HD; ++k) acc = fmaf(xs[k], W1[k * HD + t], acc);
  acc = fmaxf(acc, 0.f);
  red[t] = acc * w2[t];
  __syncthreads();
  for (int off = 64; off > 0; off >>= 1) {
    if (t < off) red[t] += red[t + off];
    __syncthreads();
  }
  if (t == 0) out[g] = red[0] + b2[0];
}

extern "C" void kernel_launch(void* const* d_in, const int* in_sizes, int n_in,
                              void* d_out, int out_size, void* d_ws, size_t ws_size,
                              hipStream_t stream) {
  (void)n_in; (void)ws_size;
  const int*   z      = (const int*)d_in[1];
  const int*   ei     = (const int*)d_in[2];
  const int*   batch  = (const int*)d_in[3];
  const float* emb    = (const float*)d_in[4];
  const float* conv_w = (const float*)d_in[5];
  const float* conv_b = (const float*)d_in[6];
  const float* w1     = (const float*)d_in[7];
  const float* b1     = (const float*)d_in[8];
  const float* w2     = (const float*)d_in[9];
  const float* b2     = (const float*)d_in[10];
  int n = in_sizes[1];
  int E = in_sizes[2] / 2;
  int G = out_size;
  const int* esrc = ei;
  const int* edst = ei + E;
  int nbuck = (n + (1 << BSH) - 1) >> BSH;

  char* p = (char*)d_ws;
  auto alloc = [&](size_t bytes) { void* r = (void*)p; p += (bytes + 255) / 256 * 256; return r; };
  unsigned* bufA   = (unsigned*)alloc((size_t)n * HD * 2);  // half
  unsigned* bufB   = (unsigned*)alloc((size_t)n * HD * 2);  // half
  float*    dinv   = (float*)alloc((size_t)n * 4);
  int*      rowptr = (int*)alloc((size_t)(n + 1) * 4);
  uint2*    pair   = (uint2*)alloc((size_t)E * 8);
  uint4*    wfrag  = (uint4*)alloc((size_t)3 * 2048 * 16);
  int*      btot   = (int*)alloc(1024 * 4);
  int*      ci     = (int*)alloc((size_t)G * 4);
  unsigned* bpool  = (unsigned*)alloc((size_t)nbuck * NBLKA * CAP * 4);
  int*      counts = (int*)alloc((size_t)nbuck * NBLKA * 4);

  int embBlocks = (n * 32 + 255) / 256;
  int ciBlocks = (n + 255) / 256;

  k_bucketA<<<NBLKA, 256, 0, stream>>>(esrc, edst, E, nbuck, bpool, counts);
  k_bhist<<<nbuck, 256, 0, stream>>>(bpool, counts, n, dinv, rowptr, btot);
  k_scanB<<<1, 256, 0, stream>>>(btot, nbuck, rowptr, n, E);
  k_bfill<<<nbuck, 256, 0, stream>>>(bpool, counts, rowptr, btot, dinv, n, pair);
  k_prep<<<24 + embBlocks + ciBlocks, 256, 0, stream>>>(conv_w, wfrag, z, (const float4*)emb,
                                                        (uint2*)bufA, batch, ci, n, embBlocks);

  const int nwaves = 4096;
  for (int l = 0; l < 3; ++l) {
    k_gemm_mfma<<<nwaves / 4, 256, 0, stream>>>((const uint4*)bufA, wfrag + (size_t)l * 2048,
                                                (uint2*)bufB, n, nwaves);
    k_agg<<<(n + 15) / 16, 256, 0, stream>>>((const uint4*)bufB, rowptr, pair, dinv,
                                             conv_b + (size_t)l * HD, (uint4*)bufA, n,
                                             l < 2 ? 1 : 0);
  }

  k_head<<<G, 128, 0, stream>>>((const __half*)bufA, ci, w1, b1, w2, b2, (float*)d_out, G);
}